// Round 1
// baseline (477.673 us; speedup 1.0000x reference)
//
#include <hip/hip_runtime.h>
#include <hip/hip_bf16.h>
#include <stdint.h>

typedef unsigned short u16;
typedef unsigned int u32;
typedef __bf16 bf16x8 __attribute__((ext_vector_type(8)));
typedef float f32x4 __attribute__((ext_vector_type(4)));

#define M_ROWS 32768   // bs*seq
#define DIM    1024    // inp_dim
#define NPROJ  64
#define NBINS  20
#define FDIM   1280    // NPROJ*NBINS
#define EDIM   1024    // emb_dim

// round-to-nearest-even f32 -> bf16 (no NaNs in this problem)
__device__ __forceinline__ u16 f2bf(float f) {
    union { float f; u32 u; } v; v.f = f;
    return (u16)((v.u + 0x7FFFu + ((v.u >> 16) & 1u)) >> 16);
}

__device__ __forceinline__ float wave_sum(float v) {
    #pragma unroll
    for (int o = 32; o > 0; o >>= 1) v += __shfl_down(v, o, 64);
    return v;
}

// ---------------------------------------------------------------------------
// K1: normalize proj_weight rows, store TRANSPOSED k-major: wnt[k][j], fp32.
// 64 blocks x 256 threads (one block per proj row).
__global__ void k_norm_w(const float* __restrict__ w, float* __restrict__ wnt) {
    int j = blockIdx.x;
    int t = threadIdx.x;
    float4 v = ((const float4*)(w + (size_t)j * DIM))[t];
    float ss = v.x*v.x + v.y*v.y + v.z*v.z + v.w*v.w;
    ss = wave_sum(ss);
    __shared__ float red[4];
    if ((t & 63) == 0) red[t >> 6] = ss;
    __syncthreads();
    float rn = 1.0f / fmaxf(sqrtf(red[0] + red[1] + red[2] + red[3]), 1e-12f);
    int k = t * 4;
    wnt[(size_t)(k+0)*NPROJ + j] = v.x * rn;
    wnt[(size_t)(k+1)*NPROJ + j] = v.y * rn;
    wnt[(size_t)(k+2)*NPROJ + j] = v.z * rn;
    wnt[(size_t)(k+3)*NPROJ + j] = v.w * rn;
}

// ---------------------------------------------------------------------------
// K2: per-row 1/max(||x||,eps). 4 rows per block (one per wave). 8192 blocks.
__global__ void k_rnx(const float* __restrict__ x, float* __restrict__ rnx) {
    int wave = threadIdx.x >> 6, lane = threadIdx.x & 63;
    size_t row = (size_t)blockIdx.x * 4 + wave;
    const float4* xr = (const float4*)(x + row * DIM);
    float ss = 0.f;
    #pragma unroll
    for (int i = 0; i < 4; i++) {
        float4 v = xr[lane + 64 * i];
        ss += v.x*v.x + v.y*v.y + v.z*v.z + v.w*v.w;
    }
    ss = wave_sum(ss);
    if (lane == 0) rnx[row] = 1.0f / fmaxf(sqrtf(ss), 1e-12f);
}

// ---------------------------------------------------------------------------
// K3: emb_weight fp32 -> bf16, same [EDIM][FDIM] layout. 1280 blocks.
__global__ void k_cvt(const float* __restrict__ s, u16* __restrict__ d) {
    int i = blockIdx.x * 256 + threadIdx.x;
    float4 v = ((const float4*)s)[i];
    ushort4 o; o.x = f2bf(v.x); o.y = f2bf(v.y); o.z = f2bf(v.z); o.w = f2bf(v.w);
    ((ushort4*)d)[i] = o;
}

// ---------------------------------------------------------------------------
// K4: GEMM1 fp32: p[m][j] = rnx[m] * sum_k x[m][k] * wnt[k][j]
// Block tile: 64 rows x 64 projs, BK=32. 256 threads, thread tile 4x4.
// wnt is pre-normalized so only the row scalar folds in.
__global__ __launch_bounds__(256) void k_gemm1(
        const float* __restrict__ x, const float* __restrict__ wnt,
        const float* __restrict__ rnx, float* __restrict__ p) {
    __shared__ float xs[32][64];   // [k][row] (transposed stage)
    __shared__ float wst[32][64];  // [k][j]
    int t = threadIdx.x;
    int bm = blockIdx.x * 64;
    int tr = t >> 4;       // 0..15 -> rows tr*4..+3
    int tc = t & 15;       // 0..15 -> projs tc*4..+3
    float acc[4][4] = {};

    for (int k0 = 0; k0 < DIM; k0 += 32) {
        #pragma unroll
        for (int u = 0; u < 2; u++) {
            int f = t * 2 + u;                 // 0..511
            // x tile: f -> row r (0..63), k-chunk kc (float4)
            int r  = f >> 3;
            int kc = (f & 7) * 4;
            float4 v = *(const float4*)(x + (size_t)(bm + r) * DIM + k0 + kc);
            xs[kc+0][r] = v.x; xs[kc+1][r] = v.y; xs[kc+2][r] = v.z; xs[kc+3][r] = v.w;
            // w tile: f -> k (0..31), j-chunk (float4), direct copy (k-major input)
            int wk = f >> 4, wj = (f & 15) * 4;
            *(float4*)&wst[wk][wj] = *(const float4*)(wnt + (size_t)(k0 + wk) * NPROJ + wj);
        }
        __syncthreads();
        #pragma unroll 8
        for (int k = 0; k < 32; k++) {
            float4 a = *(const float4*)&xs[k][tr * 4];
            float4 b = *(const float4*)&wst[k][tc * 4];
            float av[4] = {a.x, a.y, a.z, a.w};
            float bv[4] = {b.x, b.y, b.z, b.w};
            #pragma unroll
            for (int i = 0; i < 4; i++)
                #pragma unroll
                for (int j = 0; j < 4; j++)
                    acc[i][j] += av[i] * bv[j];
        }
        __syncthreads();
    }
    #pragma unroll
    for (int i = 0; i < 4; i++) {
        int row = bm + tr * 4 + i;
        float rn = rnx[row];
        float4 o = make_float4(acc[i][0]*rn, acc[i][1]*rn, acc[i][2]*rn, acc[i][3]*rn);
        *(float4*)(p + (size_t)row * NPROJ + tc * 4) = o;
    }
}

// ---------------------------------------------------------------------------
// K5: RBF + top-4 + per-group L2 normalize -> z bf16 [M_ROWS][FDIM].
// One thread per (row, proj) group. 8192 blocks x 256.
__global__ void k_act(const float* __restrict__ p, const float* __restrict__ mean,
                      u16* __restrict__ z) {
    __shared__ float mlds[FDIM];
    int t = threadIdx.x;
    #pragma unroll
    for (int i = t; i < FDIM; i += 256) mlds[i] = mean[i];
    __syncthreads();
    size_t g = (size_t)blockIdx.x * 256 + t;
    int j = (int)(g & (NPROJ - 1));
    float pv = p[g];
    float act[NBINS];
    float top0 = -1e30f, top1 = -1e30f, top2 = -1e30f, top3 = -1e30f;
    #pragma unroll
    for (int b = 0; b < NBINS; b++) {
        float d = pv - mlds[j * NBINS + b];
        float a = __expf(-50.0f * d * d);   // 0.5/sigma2 = 50
        act[b] = a;
        if (a > top3) {
            if (a > top0)      { top3 = top2; top2 = top1; top1 = top0; top0 = a; }
            else if (a > top1) { top3 = top2; top2 = top1; top1 = a; }
            else if (a > top2) { top3 = top2; top2 = a; }
            else               { top3 = a; }
        }
    }
    float ss = 0.f;
    #pragma unroll
    for (int b = 0; b < NBINS; b++) {
        float a = (act[b] >= top3) ? act[b] : 0.0f;   // keep ties (act < kth -> 0)
        act[b] = a;
        ss += a * a;
    }
    float rn = 1.0f / fmaxf(sqrtf(ss), 1e-12f);
    u32 packed[10];
    #pragma unroll
    for (int i = 0; i < 10; i++) {
        u32 lo = f2bf(act[2*i] * rn);
        u32 hi = f2bf(act[2*i+1] * rn);
        packed[i] = lo | (hi << 16);
    }
    u32* zp = (u32*)(z + g * NBINS);   // byte offset 40*g, dword aligned
    #pragma unroll
    for (int i = 0; i < 10; i++) zp[i] = packed[i];
}

// ---------------------------------------------------------------------------
// K6: GEMM2 bf16 MFMA (m97 structure): C[m][n] = sum_k A[m][k]*B[n][k]
// A = z [32768 x 1280], B = embW bf16 [1024 x 1280], C fp32 [32768 x 1024].
// 128x128 tile, BK=32, 4 waves in 2x2, each wave 4x4 of 16x16x32 MFMA.
__device__ __forceinline__ void gl_lds16(const void* g, void* l) {
    __builtin_amdgcn_global_load_lds(
        (const __attribute__((address_space(1))) void*)g,
        (__attribute__((address_space(3))) void*)l, 16, 0, 0);
}

__global__ __launch_bounds__(256) void k_gemm2(const u16* __restrict__ A,
                                               const u16* __restrict__ B,
                                               float* __restrict__ C) {
    const int K = FDIM, N = EDIM;
    __shared__ u16 As[128 * 32];
    __shared__ u16 Bs[128 * 32];
    int t = threadIdx.x;
    int lane = t & 63, wave = t >> 6;
    int bm = blockIdx.y * 128, bn = blockIdx.x * 128;
    int wm = (wave >> 1) * 64, wn = (wave & 1) * 64;
    int m16 = lane & 15, q = lane >> 4;

    f32x4 zero = {0.f, 0.f, 0.f, 0.f};
    f32x4 acc[4][4];
    #pragma unroll
    for (int i = 0; i < 4; i++)
        #pragma unroll
        for (int j = 0; j < 4; j++) acc[i][j] = zero;

    // staging map: thread t -> row sr (0..63, and +64), 8-elem chunk sc.
    // LDS byte offset = 1024*wave + 16*lane  (wave-uniform base + lane*16) ✓
    int sr = t >> 2;
    int sc = (t & 3) * 8;
    const u16* ga = A + (size_t)(bm + sr) * K + sc;
    const u16* gb = B + (size_t)(bn + sr) * K + sc;
    u16* la = &As[sr * 32 + sc];
    u16* lb = &Bs[sr * 32 + sc];

    for (int k0 = 0; k0 < K; k0 += 32) {
        gl_lds16(ga + k0,                 la);
        gl_lds16(ga + k0 + (size_t)64*K,  la + 64 * 32);
        gl_lds16(gb + k0,                 lb);
        gl_lds16(gb + k0 + (size_t)64*K,  lb + 64 * 32);
        __syncthreads();   // compiler emits vmcnt(0) drain before s_barrier
        bf16x8 af[4], bfr[4];
        #pragma unroll
        for (int i = 0; i < 4; i++)
            af[i] = *(const bf16x8*)&As[(wm + i * 16 + m16) * 32 + q * 8];
        #pragma unroll
        for (int j = 0; j < 4; j++)
            bfr[j] = *(const bf16x8*)&Bs[(wn + j * 16 + m16) * 32 + q * 8];
        #pragma unroll
        for (int i = 0; i < 4; i++)
            #pragma unroll
            for (int j = 0; j < 4; j++)
                acc[i][j] = __builtin_amdgcn_mfma_f32_16x16x32_bf16(
                    af[i], bfr[j], acc[i][j], 0, 0, 0);
        __syncthreads();
    }
    // C/D layout: col = lane&15, row = q*4 + reg  [m89-verified]
    #pragma unroll
    for (int i = 0; i < 4; i++)
        #pragma unroll
        for (int j = 0; j < 4; j++)
            #pragma unroll
            for (int r = 0; r < 4; r++) {
                int row = bm + wm + i * 16 + q * 4 + r;
                int col = bn + wn + j * 16 + m16;
                C[(size_t)row * N + col] = acc[i][j][r];
            }
}

// ---------------------------------------------------------------------------
extern "C" void kernel_launch(void* const* d_in, const int* in_sizes, int n_in,
                              void* d_out, int out_size, void* d_ws, size_t ws_size,
                              hipStream_t stream) {
    const float* x    = (const float*)d_in[0];   // [32768][1024]
    const float* pw   = (const float*)d_in[1];   // [64][1024]
    const float* mean = (const float*)d_in[2];   // [64][20]
    const float* emb  = (const float*)d_in[3];   // [1024][1280]
    float* out = (float*)d_out;                  // [32768][1024] fp32

    char* ws = (char*)d_ws;
    u16*   z    = (u16*)(ws);                    // 83,886,080 B
    float* p    = (float*)(ws + 83886080);       //  8,388,608 B
    float* wnt  = (float*)(ws + 92274688);       //    262,144 B (k-major)
    u16*   embW = (u16*)(ws + 92536832);         //  2,621,440 B
    float* rnx  = (float*)(ws + 95158272);       //    131,072 B
    // total: 95,289,344 B

    k_norm_w<<<64, 256, 0, stream>>>(pw, wnt);
    k_cvt<<<(EDIM * FDIM / 4) / 256, 256, 0, stream>>>(emb, embW);
    k_rnx<<<M_ROWS / 4, 256, 0, stream>>>(x, rnx);
    k_gemm1<<<M_ROWS / 64, 256, 0, stream>>>(x, wnt, rnx, p);
    k_act<<<(M_ROWS * NPROJ) / 256, 256, 0, stream>>>(p, mean, z);
    k_gemm2<<<dim3(EDIM / 128, M_ROWS / 128), 256, 0, stream>>>(z, embW, out);
}